// Round 12
// baseline (452.394 us; speedup 1.0000x reference)
//
#include <hip/hip_runtime.h>
#include <hip/hip_bf16.h>

typedef __bf16 bf16;
typedef __bf16 bf16x8 __attribute__((ext_vector_type(8)));
typedef __bf16 bf16x4 __attribute__((ext_vector_type(4)));
typedef float  f32x4  __attribute__((ext_vector_type(4)));

// ---------------------------------------------------------------------------
// raw barrier: flush LDS ops (lgkmcnt), DO NOT drain vmcnt — in-flight global
// loads / global_load_lds survive the barrier.
// ---------------------------------------------------------------------------
__device__ __forceinline__ void block_barrier()
{
    asm volatile("s_waitcnt lgkmcnt(0)\n\ts_barrier" ::: "memory");
}

// ---------------------------------------------------------------------------
// async global->LDS 16B per lane: LDS dst = wave-uniform base + lane*16B
// ---------------------------------------------------------------------------
#if defined(__has_builtin)
#if __has_builtin(__builtin_amdgcn_global_load_lds)
#define HAS_GLD 1
#endif
#endif
#ifndef HAS_GLD
#define HAS_GLD 0
#endif

__device__ __forceinline__ void gld_lds16(const bf16* g, bf16* lds_base)
{
#if HAS_GLD
    __builtin_amdgcn_global_load_lds(
        (const __attribute__((address_space(1))) void*)g,
        (__attribute__((address_space(3))) void*)lds_base, 16, 0, 0);
#else
    *(bf16x8*)(lds_base + (threadIdx.x & 63) * 8) = *(const bf16x8*)g;
#endif
}

// ---------------------------------------------------------------------------
// Weight transpose + fp32->bf16: src (K,N) row-major -> dst (N,K)
// ---------------------------------------------------------------------------
__global__ __launch_bounds__(256)
void transpose_cvt(const float* __restrict__ src, bf16* __restrict__ dst, int K, int N)
{
    __shared__ float t[32][33];
    const int bx = blockIdx.x, by = blockIdx.y, tid = threadIdx.x;
    const int c = tid & 31, r0 = tid >> 5;
#pragma unroll
    for (int p = 0; p < 4; p++) {
        int r = r0 + p * 8;
        t[r][c] = src[(size_t)(by * 32 + r) * N + bx * 32 + c];
    }
    __syncthreads();
#pragma unroll
    for (int p = 0; p < 4; p++) {
        int r = r0 + p * 8;
        dst[(size_t)(bx * 32 + r) * K + by * 32 + c] = (bf16)t[c][r];
    }
}

// ---------------------------------------------------------------------------
// plain fp32 -> bf16 convert, 8 elems/thread
// ---------------------------------------------------------------------------
__global__ __launch_bounds__(256)
void cvt_bf16(const float* __restrict__ src, bf16* __restrict__ dst, int n8)
{
    const int i = blockIdx.x * 256 + threadIdx.x;
    if (i >= n8) return;
    const float4* s = (const float4*)(src + (size_t)i * 8);
    float4 a = s[0], b = s[1];
    bf16x8 o;
    o[0] = (bf16)a.x; o[1] = (bf16)a.y; o[2] = (bf16)a.z; o[3] = (bf16)a.w;
    o[4] = (bf16)b.x; o[5] = (bf16)b.y; o[6] = (bf16)b.z; o[7] = (bf16)b.w;
    *(bf16x8*)(dst + (size_t)i * 8) = o;
}

// ---------------------------------------------------------------------------
// Fragment-major repacks: one coalesced 1KB burst per (group, wave) read.
// ---------------------------------------------------------------------------
__global__ __launch_bounds__(256)
void repack_wv(const bf16* __restrict__ Wvt, bf16* __restrict__ Wvf)
{
    const int t = blockIdx.x * 256 + threadIdx.x;
    const int lane = t & 63, g = t >> 6;           // g in [0, 2048)
    const int dt = g & 3, sp = (g >> 2) & 31, h = g >> 7;
    const int lm = lane & 15, q = lane >> 4;
    const bf16x8 v = *(const bf16x8*)(Wvt + (size_t)(h * 64 + dt * 16 + lm) * 1024
                                      + sp * 32 + q * 8);
    *(bf16x8*)(Wvf + (size_t)g * 512 + lane * 8) = v;
}

// Qf[((bt*16 + h)*2 + half)*512 + lane*8] = Qb[(bt*16+lm)*1024 + h*64 + half*32 + q*8]
__global__ __launch_bounds__(256)
void repack_q(const bf16* __restrict__ Qb, bf16* __restrict__ Qf)
{
    const int t = blockIdx.x * 256 + threadIdx.x;  // 1M threads
    const int lane = t & 63, g = t >> 6;           // g in [0, 16384)
    const int half = g & 1, h = (g >> 1) & 15, bt = g >> 5;
    const int lm = lane & 15, q = lane >> 4;
    const bf16x8 v = *(const bf16x8*)(Qb + (size_t)(bt * 16 + lm) * 1024
                                      + h * 64 + half * 32 + q * 8);
    *(bf16x8*)(Qf + (size_t)g * 512 + lane * 8) = v;
}

// Wkf[(((c*16+h)*4+mt)*2+half)*512 + lane*8] = Wkb[(c*64+mt*16+lm)*1024 + h*64 + half*32 + q*8]
__global__ __launch_bounds__(256)
void repack_wk(const bf16* __restrict__ Wkb, bf16* __restrict__ Wkf)
{
    const int t = blockIdx.x * 256 + threadIdx.x;  // 131072 threads
    const int lane = t & 63, g = t >> 6;           // g in [0, 2048)
    const int half = g & 1, mt = (g >> 1) & 3, h = (g >> 3) & 15, c = g >> 7;
    const int lm = lane & 15, q = lane >> 4;
    const bf16x8 v = *(const bf16x8*)(Wkb + (size_t)(c * 64 + mt * 16 + lm) * 1024
                                      + h * 64 + half * 32 + q * 8);
    *(bf16x8*)(Wkf + (size_t)g * 512 + lane * 8) = v;
}

// ---------------------------------------------------------------------------
// m97-style GEMM: C = A @ B.  A bf16 (rows via ldA), Bt bf16 (N x K, ldB).
// 128x128 tile, BK=32, global_load_lds staging, XCD swizzle (gridDim.x==8).
// Optional A2 for concat-K (gate).
// ---------------------------------------------------------------------------
template<bool TWOA>
__global__ __launch_bounds__(256)
void gemm_a97(const bf16* __restrict__ A1, const bf16* __restrict__ A2,
              const bf16* __restrict__ Bt, float* __restrict__ Cf,
              bf16* __restrict__ Cb, int Kloop, int Ksplit,
              int ldA, int ldA2, int ldB, int ldC,
              long az, long bz, long cz)
{
    __shared__ bf16 Al[128 * 32];
    __shared__ bf16 Bl[128 * 32];

    const int z = blockIdx.z;
    A1 += (size_t)z * az;
    Bt += (size_t)z * bz;
    if (Cf) Cf += (size_t)z * cz;
    if (Cb) Cb += (size_t)z * cz;

    int bx, by;
    {
        const int gy = gridDim.y;
        const int flat = blockIdx.y * gridDim.x + blockIdx.x;
        if ((gy & 7) == 0 && gridDim.x == 8) {
            const int xcd = flat & 7, slot = flat >> 3, mpx = gy >> 3;
            by = xcd * mpx + (slot >> 3);
            bx = slot & 7;
        } else { bx = blockIdx.x; by = blockIdx.y; }
    }

    const int tid = threadIdx.x;
    const int wave = tid >> 6, lane = tid & 63;
    const int m0 = by * 128, n0 = bx * 128;
    const int rl = lane >> 2;
    const int kc = (lane & 3) * 8;
    const int wm = wave >> 1, wn = wave & 1, lm = lane & 15, quad = lane >> 4;

    f32x4 acc[4][4];
#pragma unroll
    for (int i = 0; i < 4; i++)
#pragma unroll
        for (int j = 0; j < 4; j++)
#pragma unroll
            for (int r = 0; r < 4; r++) acc[i][j][r] = 0.f;

    for (int k0 = 0; k0 < Kloop; k0 += 32) {
        const bf16* Ab; int kof, ld;
        if (TWOA && k0 >= Ksplit) { Ab = A2; kof = k0 - Ksplit; ld = ldA2; }
        else                      { Ab = A1; kof = k0;          ld = ldA;  }
        const int r0 = wave * 32 + rl, r1 = r0 + 16;
        gld_lds16(Ab + (size_t)(m0 + r0) * ld + kof + kc, Al + (wave * 32) * 32);
        gld_lds16(Ab + (size_t)(m0 + r1) * ld + kof + kc, Al + (wave * 32 + 16) * 32);
        gld_lds16(Bt + (size_t)(n0 + r0) * ldB + k0 + kc, Bl + (wave * 32) * 32);
        gld_lds16(Bt + (size_t)(n0 + r1) * ldB + k0 + kc, Bl + (wave * 32 + 16) * 32);
        __syncthreads();

        bf16x8 af[4], bfr[4];
#pragma unroll
        for (int i = 0; i < 4; i++)
            af[i] = *(const bf16x8*)&Al[(wm * 64 + i * 16 + lm) * 32 + quad * 8];
#pragma unroll
        for (int j = 0; j < 4; j++)
            bfr[j] = *(const bf16x8*)&Bl[(wn * 64 + j * 16 + lm) * 32 + quad * 8];
#pragma unroll
        for (int i = 0; i < 4; i++)
#pragma unroll
            for (int j = 0; j < 4; j++)
                acc[i][j] = __builtin_amdgcn_mfma_f32_16x16x32_bf16(af[i], bfr[j], acc[i][j], 0, 0, 0);
        __syncthreads();
    }

#pragma unroll
    for (int i = 0; i < 4; i++) {
        const int rbase = m0 + wm * 64 + i * 16 + quad * 4;
#pragma unroll
        for (int j = 0; j < 4; j++) {
            const int c = n0 + wn * 64 + j * 16 + lm;
#pragma unroll
            for (int r = 0; r < 4; r++) {
                const float v = acc[i][j][r];
                const size_t idx = (size_t)(rbase + r) * ldC + c;
                if (Cf) Cf[idx] = v;
                if (Cb) Cb[idx] = (bf16)v;
            }
        }
    }
}

// ---------------------------------------------------------------------------
// Weight-stationary partial-score kernel v2: TA-coalesced.
// - wk/qf fragment loads from fragment-major Wkf/Qf (1KB bursts).
// - mk staged via own-wave global_load_lds DMA into wave-private linear
//   Ml[wave][2 b][8 k][64 i] fp32 (no barriers on mk path; one vmcnt(0)
//   per t-iter after a full iteration of compute cover).
// - Ul barriers are lgkm-only so next-tile DMA/qf loads stay in flight.
// ---------------------------------------------------------------------------
__global__ __launch_bounds__(512, 4)
void score_attn_part(const bf16* __restrict__ Qf, const bf16* __restrict__ Wkf,
                     const float* __restrict__ mk, float* __restrict__ part)
{
    __shared__ bf16  Ul[16 * 1024];   // 32KB [b16][h16][64i] swz ^(((b^h)&7)<<4)
    __shared__ float Ml[8 * 1024];    // 32KB wave-private: w*1024 + (m*8+k)*64 + i

    const int tid  = threadIdx.x;
    const int wave = tid >> 6, lane = tid & 63;
    const int lm = lane & 15, q = lane >> 4;
    const int g  = blockIdx.x;       // b-group: rows [g*128, g*128+128)
    const int c  = blockIdx.y;       // i-chunk: i in [c*64, c*64+64)
    const int i0 = c * 64;
    const int h0 = wave * 2;

    // ---- weight-stationary Wk fragments: 16 coalesced 1KB bursts
    bf16x8 wk[2][4][2];
#pragma unroll
    for (int hh = 0; hh < 2; hh++)
#pragma unroll
        for (int mt = 0; mt < 4; mt++)
#pragma unroll
            for (int half = 0; half < 2; half++)
                wk[hh][mt][half] = *(const bf16x8*)(Wkf +
                    (size_t)((((c * 16 + h0 + hh) * 4 + mt) * 2 + half)) * 512 + lane * 8);

    // DMA: wave stages its OWN rows (2w, 2w+1) x 8 k x 64 i = 4KB = 4 issues.
    // issue s, lane l: chunk = s*4 + (l>>4); m = chunk>>3, k = chunk&7;
    // src 16B at mk[b0 + 2w + m][k*1024 + i0 + (l&15)*4]; dst linear.
    const int choff = lane >> 4, lli = (lane & 15) * 4;

    float* pbase = part + ((size_t)c << 20);   // c * 8192*128

    // ---- prologue: qf(0) + DMA(0)
    int bt = g * 8;                            // b-tile index (b0 = bt*16)
    bf16x8 qf[2][2];
#pragma unroll
    for (int hh = 0; hh < 2; hh++)
#pragma unroll
        for (int half = 0; half < 2; half++)
            qf[hh][half] = *(const bf16x8*)(Qf +
                (size_t)(((bt * 16 + h0 + hh) * 2 + half)) * 512 + lane * 8);
#pragma unroll
    for (int s = 0; s < 4; s++) {
        const int chunk = s * 4 + choff;
        gld_lds16((const bf16*)(mk + (size_t)(bt * 16 + 2 * wave + (chunk >> 3)) * 8192
                                + (chunk & 7) * 1024 + i0 + lli),
                  (bf16*)&Ml[wave * 1024 + s * 256]);
    }

    for (int t = 0; t < 8; ++t) {
        const int b0 = g * 128 + t * 16;
        const int btn = (t < 7) ? bt + 1 : bt;   // next tile (clamped; tail unused)

        // ---- 1. all vmem (DMA(t), qf(t)) landed; full prev-iter of cover
        asm volatile("s_waitcnt vmcnt(0)" ::: "memory");
        __builtin_amdgcn_sched_barrier(0);

        // ---- 2. mb B-frags from wave-private Ml (+cvt)
        bf16x8 mbr[2][2];
#pragma unroll
        for (int lb = 0; lb < 2; lb++) {
            const int base = wave * 1024 + (lb * 8 + (lm & 7)) * 64;
            const f32x4 a0 = *(const f32x4*)&Ml[base + q * 8];
            const f32x4 a1 = *(const f32x4*)&Ml[base + q * 8 + 4];
            const f32x4 b0v = *(const f32x4*)&Ml[base + 32 + q * 8];
            const f32x4 b1v = *(const f32x4*)&Ml[base + 32 + q * 8 + 4];
            bf16x8 m0, m1;
            m0[0] = (bf16)a0[0]; m0[1] = (bf16)a0[1]; m0[2] = (bf16)a0[2]; m0[3] = (bf16)a0[3];
            m0[4] = (bf16)a1[0]; m0[5] = (bf16)a1[1]; m0[6] = (bf16)a1[2]; m0[7] = (bf16)a1[3];
            m1[0] = (bf16)b0v[0]; m1[1] = (bf16)b0v[1]; m1[2] = (bf16)b0v[2]; m1[3] = (bf16)b0v[3];
            m1[4] = (bf16)b1v[0]; m1[5] = (bf16)b1v[1]; m1[6] = (bf16)b1v[2]; m1[7] = (bf16)b1v[3];
            mbr[lb][0] = m0; mbr[lb][1] = m1;
        }
        // reads must complete before DMA(t+1) overwrites (wave-local fence)
        asm volatile("s_waitcnt lgkmcnt(0)" ::: "memory");
        __builtin_amdgcn_sched_barrier(0);

        // ---- 3. U-gen: C[i][b] tiles -> Ul (consumes qf(t))
#pragma unroll
        for (int hh = 0; hh < 2; hh++) {
            const int h = h0 + hh;
#pragma unroll
            for (int mt = 0; mt < 4; mt++) {
                f32x4 c4;
                c4[0] = 0.f; c4[1] = 0.f; c4[2] = 0.f; c4[3] = 0.f;
                c4 = __builtin_amdgcn_mfma_f32_16x16x32_bf16(wk[hh][mt][0], qf[hh][0], c4, 0, 0, 0);
                c4 = __builtin_amdgcn_mfma_f32_16x16x32_bf16(wk[hh][mt][1], qf[hh][1], c4, 0, 0, 0);
                bf16x4 o;
                o[0] = (bf16)c4[0]; o[1] = (bf16)c4[1]; o[2] = (bf16)c4[2]; o[3] = (bf16)c4[3];
                *(bf16x4*)((char*)Ul + ((((lm * 16 + h) * 64 + mt * 16 + q * 4) * 2)
                                        ^ (((lm ^ h) & 7) << 4))) = o;
            }
        }

        // ---- 4. issue qf(t+1) + DMA(t+1) (ride across the barriers)
#pragma unroll
        for (int hh = 0; hh < 2; hh++)
#pragma unroll
            for (int half = 0; half < 2; half++)
                qf[hh][half] = *(const bf16x8*)(Qf +
                    (size_t)(((btn * 16 + h0 + hh) * 2 + half)) * 512 + lane * 8);
#pragma unroll
        for (int s = 0; s < 4; s++) {
            const int chunk = s * 4 + choff;
            gld_lds16((const bf16*)(mk + (size_t)(btn * 16 + 2 * wave + (chunk >> 3)) * 8192
                                    + (chunk & 7) * 1024 + i0 + lli),
                      (bf16*)&Ml[wave * 1024 + s * 256]);
        }

        block_barrier();   // Ul visible (lgkm only; vmem stays in flight)

        // ---- 5. score MFMA + partial store
#pragma unroll
        for (int lb = 0; lb < 2; lb++) {
            const int bb = wave * 2 + lb;
            const bf16x8 ua0 = *(const bf16x8*)((char*)Ul +
                ((((bb * 16 + lm) * 64 + q * 8) * 2) ^ (((bb ^ lm) & 7) << 4)));
            const bf16x8 ua1 = *(const bf16x8*)((char*)Ul +
                ((((bb * 16 + lm) * 64 + 32 + q * 8) * 2) ^ (((bb ^ lm) & 7) << 4)));

            f32x4 s4;
            s4[0] = 0.f; s4[1] = 0.f; s4[2] = 0.f; s4[3] = 0.f;
            s4 = __builtin_amdgcn_mfma_f32_16x16x32_bf16(ua0, mbr[lb][0], s4, 0, 0, 0);
            s4 = __builtin_amdgcn_mfma_f32_16x16x32_bf16(ua1, mbr[lb][1], s4, 0, 0, 0);

            if (lm < 8) {
                float* pp = pbase + (size_t)(b0 + bb) * 128 + lm;
#pragma unroll
                for (int r = 0; r < 4; r++) pp[(q * 4 + r) * 8] = s4[r];
            }
        }
        block_barrier();   // Ul consumed; safe to overwrite next iter

        bt = btn;
    }
}

// ---------------------------------------------------------------------------
// reduce 16 i-chunk partials + softmax over k -> attn (B x 16 x 8 fp32)
// ---------------------------------------------------------------------------
__global__ __launch_bounds__(256)
void reduce_softmax(const float* __restrict__ part, float* __restrict__ attn)
{
    const int t = blockIdx.x * 256 + threadIdx.x;   // (b*16 + h)
    const float* p = part + (size_t)t * 8;
    float s[8] = {0.f, 0.f, 0.f, 0.f, 0.f, 0.f, 0.f, 0.f};
#pragma unroll
    for (int c = 0; c < 16; ++c) {
        const f32x4 a = *(const f32x4*)(p + ((size_t)c << 20));
        const f32x4 b = *(const f32x4*)(p + ((size_t)c << 20) + 4);
        s[0] += a[0]; s[1] += a[1]; s[2] += a[2]; s[3] += a[3];
        s[4] += b[0]; s[5] += b[1]; s[6] += b[2]; s[7] += b[3];
    }
#pragma unroll
    for (int k = 0; k < 8; k++) s[k] *= 0.125f;     // DH^-0.5
    float mx = s[0];
#pragma unroll
    for (int k = 1; k < 8; k++) mx = fmaxf(mx, s[k]);
    float den = 0.f;
#pragma unroll
    for (int k = 0; k < 8; k++) { s[k] = __expf(s[k] - mx); den += s[k]; }
    const float inv = 1.f / den;
    f32x4 o0, o1;
    o0[0] = s[0] * inv; o0[1] = s[1] * inv; o0[2] = s[2] * inv; o0[3] = s[3] * inv;
    o1[0] = s[4] * inv; o1[1] = s[5] * inv; o1[2] = s[6] * inv; o1[3] = s[7] * inv;
    *(f32x4*)(attn + (size_t)t * 8)     = o0;
    *(f32x4*)(attn + (size_t)t * 8 + 4) = o1;
}

// ---------------------------------------------------------------------------
// Fused apply kernel v10 (verified R11): fragment-major Wvf + DMA mv staging.
// ---------------------------------------------------------------------------
__global__ __launch_bounds__(512, 4)
void apply_attn(const float* __restrict__ attn, const float* __restrict__ mv,
                const bf16* __restrict__ Wvf, bf16* __restrict__ OH)
{
    __shared__ float Vl32[3][4096];    // 3x16KB [16 rows][8 k][32 i] fp32, LINEAR
    __shared__ bf16  Wl[16 * 16 * 32]; // 16KB [b][h][32 i] swz ^(((b^h)&7)<<4)

    const int tid  = threadIdx.x;
    const int wave = tid >> 6, lane = tid & 63;
    const int lm = lane & 15, q = lane >> 4;
    const int b0 = blockIdx.x * 16;
    const int h0 = wave * 2;

    const int gk = lane >> 3, gi4 = (lane & 7) * 4;

    bf16x8 afv[2][2];
#pragma unroll
    for (int lb = 0; lb < 2; lb++) {
        const float* ap = attn + (size_t)(b0 + wave * 2 + lb) * 128 + lm * 8;
        const float4 x = *(const float4*)(ap);
        const float4 y = *(const float4*)(ap + 4);
        bf16 a8[8];
        a8[0] = (bf16)x.x; a8[1] = (bf16)x.y; a8[2] = (bf16)x.z; a8[3] = (bf16)x.w;
        a8[4] = (bf16)y.x; a8[5] = (bf16)y.y; a8[6] = (bf16)y.z; a8[7] = (bf16)y.w;
#pragma unroll
        for (int mt = 0; mt < 2; mt++) {
            bf16x8 t;
#pragma unroll
            for (int j = 0; j < 8; j++) t[j] = (q == mt) ? a8[j] : (bf16)0.f;
            afv[lb][mt] = t;
        }
    }

    f32x4 oacc[2][4];
#pragma unroll
    for (int i = 0; i < 2; i++)
#pragma unroll
        for (int j = 0; j < 4; j++)
#pragma unroll
            for (int r = 0; r < 4; r++) oacc[i][j][r] = 0.f;

#pragma unroll
    for (int m = 0; m < 2; m++) {
        const int row = 2 * wave + m;
        gld_lds16((const bf16*)(mv + (size_t)(b0 + row) * 8192 + gk * 1024 + gi4),
                  (bf16*)&Vl32[0][row * 256]);
    }
#pragma unroll
    for (int m = 0; m < 2; m++) {
        const int row = 2 * wave + m;
        gld_lds16((const bf16*)(mv + (size_t)(b0 + row) * 8192 + gk * 1024 + 32 + gi4),
                  (bf16*)&Vl32[1][row * 256]);
    }

    for (int sp = 0; sp < 32; ++sp) {
        const int ni = (sp + 2 < 32) ? sp * 32 + 64 : 0;
        const int cb = sp % 3, nb = (sp + 2) % 3;

        bf16x8 wb[2][4];
#pragma unroll
        for (int hh = 0; hh < 2; hh++) {
            const int h = h0 + hh;
#pragma unroll
            for (int dt = 0; dt < 4; dt++)
                wb[hh][dt] = *(const bf16x8*)(Wvf +
                    ((((size_t)h * 32 + sp) * 4 + dt) * 512 + lane * 8));
        }
        __builtin_amdgcn_sched_barrier(0);

#pragma unroll
        for (int m = 0; m < 2; m++) {
            const int row = 2 * wave + m;
            gld_lds16((const bf16*)(mv + (size_t)(b0 + row) * 8192 + gk * 1024 + ni + gi4),
                      (bf16*)&Vl32[nb][row * 256]);
        }
        __builtin_amdgcn_sched_barrier(0);

        asm volatile("s_waitcnt vmcnt(12)" ::: "memory");
        __builtin_amdgcn_sched_barrier(0);
#pragma unroll
        for (int lb = 0; lb < 2; lb++) {
            const int row = 2 * wave + lb;
            const int il = (q & 1) * 16 + lm;
            float v[8];
#pragma unroll
            for (int k = 0; k < 8; k++) v[k] = Vl32[cb][row * 256 + k * 32 + il];
            bf16x8 avf;
#pragma unroll
            for (int k = 0; k < 8; k++) avf[k] = (bf16)v[k];
#pragma unroll
            for (int mt = 0; mt < 2; mt++) {
                f32x4 c;
                c[0] = 0.f; c[1] = 0.f; c[2] = 0.f; c[3] = 0.f;
                c = __builtin_amdgcn_mfma_f32_16x16x32_bf16(avf, afv[lb][mt], c, 0, 0, 0);
                bf16x4 o;
                o[0] = (bf16)c[0]; o[1] = (bf16)c[1]; o[2] = (bf16)c[2]; o[3] = (bf16)c[3];
                *(bf16x4*)((char*)Wl + ((((row * 16 + lm) * 32 + mt * 16 + q * 4) * 2)
                                        ^ (((row ^ lm) & 7) << 4))) = o;
            }
        }
        block_barrier();

        asm volatile("s_waitcnt vmcnt(2)" ::: "memory");
        __builtin_amdgcn_sched_barrier(0);
#pragma unroll
        for (int hh = 0; hh < 2; hh++) {
            const int h = h0 + hh;
            const bf16x8 wa = *(const bf16x8*)((char*)Wl +
                ((((lm * 16 + h) * 32 + q * 8) * 2) ^ (((lm ^ h) & 7) << 4)));
#pragma unroll
            for (int dt = 0; dt < 4; dt++)
                oacc[hh][dt] = __builtin_amdgcn_mfma_f32_16x16x32_bf16(wa, wb[hh][dt], oacc[hh][dt], 0, 0, 0);
        }
        block_barrier();
    }

#pragma unroll
    for (int hh = 0; hh < 2; hh++) {
        const int h = h0 + hh;
#pragma unroll
        for (int dt = 0; dt < 4; dt++) {
#pragma unroll
            for (int r = 0; r < 4; r++)
                OH[(size_t)(b0 + q * 4 + r) * 1024 + h * 64 + dt * 16 + lm] = (bf16)oacc[hh][dt][r];
        }
    }
}

// ---------------------------------------------------------------------------
// sigmoid gate + residual + LayerNorm. One block per row.
// ---------------------------------------------------------------------------
__global__ __launch_bounds__(256)
void gate_ln_kernel(const float* __restrict__ hs, const float* __restrict__ mo,
                    const float* __restrict__ z,  const float* __restrict__ bg,
                    const float* __restrict__ lng, const float* __restrict__ lnb,
                    float* __restrict__ out)
{
    __shared__ float s1[4], s2[4];
    const int tid = threadIdx.x;
    const size_t base = (size_t)blockIdx.x * 1024 + tid * 4;

    const float4 h4 = *(const float4*)&hs[base];
    const float4 m4 = *(const float4*)&mo[base];
    const float4 z4 = *(const float4*)&z[base];
    const float4 bg4 = *(const float4*)&bg[tid * 4];

    float a[4];
    {
        const float g0 = 1.f / (1.f + __expf(-(z4.x + bg4.x)));
        const float g1 = 1.f / (1.f + __expf(-(z4.y + bg4.y)));
        const float g2 = 1.f / (1.f + __expf(-(z4.z + bg4.z)));
        const float g3 = 1.f / (1.f + __expf(-(z4.w + bg4.w)));
        a[0] = h4.x + g0 * m4.x;
        a[1] = h4.y + g1 * m4.y;
        a[2] = h4.z + g2 * m4.z;
        a[3] = h4.w + g3 * m4.w;
    }
    float sum = a[0] + a[1] + a[2] + a[3];
    float sq  = a[0]*a[0] + a[1]*a[1] + a[2]*a[2] + a[3]*a[3];
#pragma unroll
    for (int off = 32; off >= 1; off >>= 1) {
        sum += __shfl_xor(sum, off);
        sq  += __shfl_xor(sq,  off);
    }
    const int wave = tid >> 6;
    if ((tid & 63) == 0) { s1[wave] = sum; s2[wave] = sq; }
    __syncthreads();
    const float mean = (s1[0] + s1[1] + s1[2] + s1[3]) * (1.f / 1024.f);
    const float var  = (s2[0] + s2[1] + s2[2] + s2[3]) * (1.f / 1024.f) - mean * mean;
    const float inv  = rsqrtf(var + 1e-5f);

    const float4 g4 = *(const float4*)&lng[tid * 4];
    const float4 b4 = *(const float4*)&lnb[tid * 4];
    float4 o;
    o.x = (a[0] - mean) * inv * g4.x + b4.x;
    o.y = (a[1] - mean) * inv * g4.y + b4.y;
    o.z = (a[2] - mean) * inv * g4.z + b4.z;
    o.w = (a[3] - mean) * inv * g4.w + b4.w;
    *(float4*)&out[base] = o;
}

// ---------------------------------------------------------------------------
extern "C" void kernel_launch(void* const* d_in, const int* in_sizes, int n_in,
                              void* d_out, int out_size, void* d_ws, size_t ws_size,
                              hipStream_t stream)
{
    const float* hs  = (const float*)d_in[0];
    const float* mk  = (const float*)d_in[1];
    const float* mv  = (const float*)d_in[2];
    const float* Wq  = (const float*)d_in[3];
    const float* Wk  = (const float*)d_in[4];
    const float* Wv  = (const float*)d_in[5];
    const float* Wo  = (const float*)d_in[6];
    const float* Wg  = (const float*)d_in[7];
    const float* bg  = (const float*)d_in[8];
    const float* lng = (const float*)d_in[9];
    const float* lnb = (const float*)d_in[10];
    float* out = (float*)d_out;

    const int B = 8192;
    const dim3 tb(256);

    char* ws = (char*)d_ws;
    bf16*  Wq_t = (bf16*)(ws);                        // 2 MB  (1024x1024, N x K)
    bf16*  Wv_t = (bf16*)(ws + ((size_t)2  << 20));   // 2 MB
    bf16*  Wo_t = (bf16*)(ws + ((size_t)4  << 20));   // 2 MB
    bf16*  Wg_t = (bf16*)(ws + ((size_t)6  << 20));   // 4 MB  (1024x2048)
    bf16*  Wk_b = (bf16*)(ws + ((size_t)10 << 20));   // 2 MB  (1024x1024, NOT transposed)
    bf16*  hs_b = (bf16*)(ws + ((size_t)12 << 20));   // 16 MB (8192x1024)
    bf16*  Qb   = (bf16*)(ws + ((size_t)28 << 20));   // 16 MB
    bf16*  OH   = (bf16*)(ws + ((size_t)44 << 20));   // 16 MB
    float* Mo   = (float*)(ws + ((size_t)60 << 20));  // 32 MB
    bf16*  Mo_b = (bf16*)(ws + ((size_t)92 << 20));   // 16 MB
    float* Zb   = (float*)(ws + ((size_t)108 << 20)); // 32 MB
    float* At   = (float*)(ws + ((size_t)140 << 20)); // 4 MB  (8192x16x8 fp32)
    float* Atp  = (float*)(ws + ((size_t)144 << 20)); // 64 MB (16 x 8192x16x8 fp32)
    bf16*  Wvf  = (bf16*)(ws + ((size_t)208 << 20));  // 2 MB  (fragment-major Wv)
    bf16*  Wkf  = (bf16*)(ws + ((size_t)210 << 20));  // 2 MB  (fragment-major Wk)
    bf16*  Qf   = (bf16*)(ws + ((size_t)212 << 20));  // 16 MB (fragment-major Q)

    transpose_cvt<<<dim3(32, 32), tb, 0, stream>>>(Wq, Wq_t, 1024, 1024);
    transpose_cvt<<<dim3(32, 32), tb, 0, stream>>>(Wv, Wv_t, 1024, 1024);
    transpose_cvt<<<dim3(32, 32), tb, 0, stream>>>(Wo, Wo_t, 1024, 1024);
    transpose_cvt<<<dim3(32, 64), tb, 0, stream>>>(Wg, Wg_t, 2048, 1024);
    cvt_bf16<<<dim3(1024 * 1024 / 8 / 256), tb, 0, stream>>>(Wk, Wk_b, 1024 * 1024 / 8);
    cvt_bf16<<<dim3(B * 1024 / 8 / 256), tb, 0, stream>>>(hs, hs_b, B * 1024 / 8);
    repack_wv<<<dim3(512), tb, 0, stream>>>(Wv_t, Wvf);
    repack_wk<<<dim3(512), tb, 0, stream>>>(Wk_b, Wkf);

    // Q = hs @ Wq -> bf16 (B x 1024)
    gemm_a97<false><<<dim3(8, 64, 1), tb, 0, stream>>>(
        hs_b, nullptr, Wq_t, nullptr, Qb,
        1024, 1024, 1024, 0, 1024, 1024, 0, 0, 0);
    // fragment-major Q for the score kernel
    repack_q<<<dim3(4096), tb, 0, stream>>>(Qb, Qf);
    // weight-stationary partial scores (16 i-chunks x 64 b-groups)
    score_attn_part<<<dim3(64, 16), dim3(512), 0, stream>>>(Qf, Wkf, mk, Atp);
    // reduce chunks + softmax -> attn
    reduce_softmax<<<dim3(512), tb, 0, stream>>>(Atp, At);
    // fused: W_mix-gen + V-proj -> OH (B x 1024 bf16)
    apply_attn<<<dim3(B / 16), dim3(512), 0, stream>>>(At, mv, Wvf, OH);
    // memory_out = OH @ Wo -> fp32 Mo + bf16 Mo_b
    gemm_a97<false><<<dim3(8, 64, 1), tb, 0, stream>>>(
        OH, nullptr, Wo_t, Mo, Mo_b,
        1024, 1024, 1024, 0, 1024, 1024, 0, 0, 0);
    // z = [hs, Mo] @ Wg -> fp32
    gemm_a97<true><<<dim3(8, 64, 1), tb, 0, stream>>>(
        hs_b, Mo_b, Wg_t, Zb, nullptr,
        2048, 1024, 1024, 1024, 2048, 1024, 0, 0, 0);
    // gate + residual + LayerNorm
    gate_ln_kernel<<<dim3(B), tb, 0, stream>>>(
        hs, Mo, Zb, bg, lng, lnb, out);
}

// Round 13
// 426.271 us; speedup vs baseline: 1.0613x; 1.0613x over previous
//
#include <hip/hip_runtime.h>
#include <hip/hip_bf16.h>

typedef __bf16 bf16;
typedef __bf16 bf16x8 __attribute__((ext_vector_type(8)));
typedef __bf16 bf16x4 __attribute__((ext_vector_type(4)));
typedef float  f32x4  __attribute__((ext_vector_type(4)));

// ---------------------------------------------------------------------------
// raw barrier: flush LDS ops (lgkmcnt), DO NOT drain vmcnt — in-flight global
// loads / global_load_lds survive the barrier.
// ---------------------------------------------------------------------------
__device__ __forceinline__ void block_barrier()
{
    asm volatile("s_waitcnt lgkmcnt(0)\n\ts_barrier" ::: "memory");
}

// ---------------------------------------------------------------------------
// async global->LDS 16B per lane: LDS dst = wave-uniform base + lane*16B
// ---------------------------------------------------------------------------
#if defined(__has_builtin)
#if __has_builtin(__builtin_amdgcn_global_load_lds)
#define HAS_GLD 1
#endif
#endif
#ifndef HAS_GLD
#define HAS_GLD 0
#endif

__device__ __forceinline__ void gld_lds16(const bf16* g, bf16* lds_base)
{
#if HAS_GLD
    __builtin_amdgcn_global_load_lds(
        (const __attribute__((address_space(1))) void*)g,
        (__attribute__((address_space(3))) void*)lds_base, 16, 0, 0);
#else
    *(bf16x8*)(lds_base + (threadIdx.x & 63) * 8) = *(const bf16x8*)g;
#endif
}

// ---------------------------------------------------------------------------
// Weight transpose + fp32->bf16: src (K,N) row-major -> dst (N,K)
// ---------------------------------------------------------------------------
__global__ __launch_bounds__(256)
void transpose_cvt(const float* __restrict__ src, bf16* __restrict__ dst, int K, int N)
{
    __shared__ float t[32][33];
    const int bx = blockIdx.x, by = blockIdx.y, tid = threadIdx.x;
    const int c = tid & 31, r0 = tid >> 5;
#pragma unroll
    for (int p = 0; p < 4; p++) {
        int r = r0 + p * 8;
        t[r][c] = src[(size_t)(by * 32 + r) * N + bx * 32 + c];
    }
    __syncthreads();
#pragma unroll
    for (int p = 0; p < 4; p++) {
        int r = r0 + p * 8;
        dst[(size_t)(bx * 32 + r) * K + by * 32 + c] = (bf16)t[c][r];
    }
}

// ---------------------------------------------------------------------------
// plain fp32 -> bf16 convert, 8 elems/thread
// ---------------------------------------------------------------------------
__global__ __launch_bounds__(256)
void cvt_bf16(const float* __restrict__ src, bf16* __restrict__ dst, int n8)
{
    const int i = blockIdx.x * 256 + threadIdx.x;
    if (i >= n8) return;
    const float4* s = (const float4*)(src + (size_t)i * 8);
    float4 a = s[0], b = s[1];
    bf16x8 o;
    o[0] = (bf16)a.x; o[1] = (bf16)a.y; o[2] = (bf16)a.z; o[3] = (bf16)a.w;
    o[4] = (bf16)b.x; o[5] = (bf16)b.y; o[6] = (bf16)b.z; o[7] = (bf16)b.w;
    *(bf16x8*)(dst + (size_t)i * 8) = o;
}

// ---------------------------------------------------------------------------
// Fragment-major repacks: one coalesced 1KB burst per (group, wave) read.
// ---------------------------------------------------------------------------
__global__ __launch_bounds__(256)
void repack_wv(const bf16* __restrict__ Wvt, bf16* __restrict__ Wvf)
{
    const int t = blockIdx.x * 256 + threadIdx.x;
    const int lane = t & 63, g = t >> 6;           // g in [0, 2048)
    const int dt = g & 3, sp = (g >> 2) & 31, h = g >> 7;
    const int lm = lane & 15, q = lane >> 4;
    const bf16x8 v = *(const bf16x8*)(Wvt + (size_t)(h * 64 + dt * 16 + lm) * 1024
                                      + sp * 32 + q * 8);
    *(bf16x8*)(Wvf + (size_t)g * 512 + lane * 8) = v;
}

// Qf[((bt*16 + h)*2 + half)*512 + lane*8] = Qb[(bt*16+lm)*1024 + h*64 + half*32 + q*8]
__global__ __launch_bounds__(256)
void repack_q(const bf16* __restrict__ Qb, bf16* __restrict__ Qf)
{
    const int t = blockIdx.x * 256 + threadIdx.x;  // 1M threads
    const int lane = t & 63, g = t >> 6;           // g in [0, 16384)
    const int half = g & 1, h = (g >> 1) & 15, bt = g >> 5;
    const int lm = lane & 15, q = lane >> 4;
    const bf16x8 v = *(const bf16x8*)(Qb + (size_t)(bt * 16 + lm) * 1024
                                      + h * 64 + half * 32 + q * 8);
    *(bf16x8*)(Qf + (size_t)g * 512 + lane * 8) = v;
}

// Wkf2[(((sp*2+mt)*16+h)*2+half)*512 + lane*8] =
//     Wkb[(sp*32+mt*16+lm)*1024 + h*64 + half*32 + q*8]   (32-i superstep frags)
__global__ __launch_bounds__(256)
void repack_wk2(const bf16* __restrict__ Wkb, bf16* __restrict__ Wkf)
{
    const int t = blockIdx.x * 256 + threadIdx.x;  // 131072 threads
    const int lane = t & 63, g = t >> 6;           // g in [0, 2048)
    const int half = g & 1, h = (g >> 1) & 15, mt = (g >> 5) & 1, sp = g >> 6;
    const int lm = lane & 15, q = lane >> 4;
    const bf16x8 v = *(const bf16x8*)(Wkb + (size_t)(sp * 32 + mt * 16 + lm) * 1024
                                      + h * 64 + half * 32 + q * 8);
    *(bf16x8*)(Wkf + (size_t)g * 512 + lane * 8) = v;
}

// ---------------------------------------------------------------------------
// m97-style GEMM: C = A @ B.  A bf16 (rows via ldA), Bt bf16 (N x K, ldB).
// 128x128 tile, BK=32, global_load_lds staging, XCD swizzle (gridDim.x==8).
// Optional A2 for concat-K (gate).
// ---------------------------------------------------------------------------
template<bool TWOA>
__global__ __launch_bounds__(256)
void gemm_a97(const bf16* __restrict__ A1, const bf16* __restrict__ A2,
              const bf16* __restrict__ Bt, float* __restrict__ Cf,
              bf16* __restrict__ Cb, int Kloop, int Ksplit,
              int ldA, int ldA2, int ldB, int ldC,
              long az, long bz, long cz)
{
    __shared__ bf16 Al[128 * 32];
    __shared__ bf16 Bl[128 * 32];

    const int z = blockIdx.z;
    A1 += (size_t)z * az;
    Bt += (size_t)z * bz;
    if (Cf) Cf += (size_t)z * cz;
    if (Cb) Cb += (size_t)z * cz;

    int bx, by;
    {
        const int gy = gridDim.y;
        const int flat = blockIdx.y * gridDim.x + blockIdx.x;
        if ((gy & 7) == 0 && gridDim.x == 8) {
            const int xcd = flat & 7, slot = flat >> 3, mpx = gy >> 3;
            by = xcd * mpx + (slot >> 3);
            bx = slot & 7;
        } else { bx = blockIdx.x; by = blockIdx.y; }
    }

    const int tid = threadIdx.x;
    const int wave = tid >> 6, lane = tid & 63;
    const int m0 = by * 128, n0 = bx * 128;
    const int rl = lane >> 2;
    const int kc = (lane & 3) * 8;
    const int wm = wave >> 1, wn = wave & 1, lm = lane & 15, quad = lane >> 4;

    f32x4 acc[4][4];
#pragma unroll
    for (int i = 0; i < 4; i++)
#pragma unroll
        for (int j = 0; j < 4; j++)
#pragma unroll
            for (int r = 0; r < 4; r++) acc[i][j][r] = 0.f;

    for (int k0 = 0; k0 < Kloop; k0 += 32) {
        const bf16* Ab; int kof, ld;
        if (TWOA && k0 >= Ksplit) { Ab = A2; kof = k0 - Ksplit; ld = ldA2; }
        else                      { Ab = A1; kof = k0;          ld = ldA;  }
        const int r0 = wave * 32 + rl, r1 = r0 + 16;
        gld_lds16(Ab + (size_t)(m0 + r0) * ld + kof + kc, Al + (wave * 32) * 32);
        gld_lds16(Ab + (size_t)(m0 + r1) * ld + kof + kc, Al + (wave * 32 + 16) * 32);
        gld_lds16(Bt + (size_t)(n0 + r0) * ldB + k0 + kc, Bl + (wave * 32) * 32);
        gld_lds16(Bt + (size_t)(n0 + r1) * ldB + k0 + kc, Bl + (wave * 32 + 16) * 32);
        __syncthreads();

        bf16x8 af[4], bfr[4];
#pragma unroll
        for (int i = 0; i < 4; i++)
            af[i] = *(const bf16x8*)&Al[(wm * 64 + i * 16 + lm) * 32 + quad * 8];
#pragma unroll
        for (int j = 0; j < 4; j++)
            bfr[j] = *(const bf16x8*)&Bl[(wn * 64 + j * 16 + lm) * 32 + quad * 8];
#pragma unroll
        for (int i = 0; i < 4; i++)
#pragma unroll
            for (int j = 0; j < 4; j++)
                acc[i][j] = __builtin_amdgcn_mfma_f32_16x16x32_bf16(af[i], bfr[j], acc[i][j], 0, 0, 0);
        __syncthreads();
    }

#pragma unroll
    for (int i = 0; i < 4; i++) {
        const int rbase = m0 + wm * 64 + i * 16 + quad * 4;
#pragma unroll
        for (int j = 0; j < 4; j++) {
            const int c = n0 + wn * 64 + j * 16 + lm;
#pragma unroll
            for (int r = 0; r < 4; r++) {
                const float v = acc[i][j][r];
                const size_t idx = (size_t)(rbase + r) * ldC + c;
                if (Cf) Cf[idx] = v;
                if (Cb) Cb[idx] = (bf16)v;
            }
        }
    }
}

// ---------------------------------------------------------------------------
// Fused score kernel v3: apply-v10-style structure.
// One block per 16 b-rows; 32 supersteps over i (32 each).
// - Q frags loaded ONCE (fragment-major Qf).
// - Wk slice frags per superstep from Wkf2 (2MB, L2/L3-resident, 1KB bursts).
// - mk via own-wave DMA into double-buffered Ml[2][16b][8 g4][8 k][4 i]
//   (i-major-chunk permuted source -> bank index kk*4, max 4-way).
// - sacc accumulates across supersteps in regs; inline softmax -> attn.
// Waits: vmcnt(2) before U-gen (wk + own DMA landed, next DMA in flight).
// ---------------------------------------------------------------------------
__global__ __launch_bounds__(512, 4)
void score_attn(const bf16* __restrict__ Qf, const bf16* __restrict__ Wkf,
                const float* __restrict__ mk, float* __restrict__ attn)
{
    __shared__ bf16  Ul[16 * 16 * 32]; // 16KB [b][h][32i] swz ^(((b^h)&7)<<4)
    __shared__ float Ml[2][4096];      // 2x16KB [16b][8 g4][8 k][4 i]

    const int tid  = threadIdx.x;
    const int wave = tid >> 6, lane = tid & 63;
    const int lm = lane & 15, q = lane >> 4;
    const int bt = blockIdx.x;         // rows [bt*16, bt*16+16)
    const int h0 = wave * 2;

    // DMA mapping: wave stages its own rows 2w, 2w+1 (1KB = 1 issue each).
    // lane l -> k = l&7, g4 = l>>3; src 16B = mk[b][k*1024 + i0 + g4*4]
    // dst word l*4 = g4*32 + k*4  ->  layout [g4][k][4i]
    const int gk = lane & 7, gg4 = lane >> 3;

    // ---- persistent Q B-frags (coalesced 1KB bursts, loaded once)
    bf16x8 qf[2][2];
#pragma unroll
    for (int hh = 0; hh < 2; hh++)
#pragma unroll
        for (int half = 0; half < 2; half++)
            qf[hh][half] = *(const bf16x8*)(Qf +
                (size_t)((bt * 16 + h0 + hh) * 2 + half) * 512 + lane * 8);

    f32x4 sacc[2];
#pragma unroll
    for (int lb = 0; lb < 2; lb++)
#pragma unroll
        for (int r = 0; r < 4; r++) sacc[lb][r] = 0.f;

    // ---- prologue: DMA slice 0
#pragma unroll
    for (int m = 0; m < 2; m++) {
        const int row = 2 * wave + m;
        gld_lds16((const bf16*)(mk + (size_t)(bt * 16 + row) * 8192 + gk * 1024 + gg4 * 4),
                  (bf16*)&Ml[0][row * 256]);
    }

    for (int sp = 0; sp < 32; ++sp) {
        const int ni = (sp + 1 < 32) ? (sp + 1) * 32 : 0;  // tail wraps (unused)
        const int cb = sp & 1, nb = cb ^ 1;

        // ---- 1. Wk slice frags (oldest): 8 coalesced 1KB bursts
        bf16x8 wk[2][2][2];
#pragma unroll
        for (int hh = 0; hh < 2; hh++)
#pragma unroll
            for (int mt = 0; mt < 2; mt++)
#pragma unroll
                for (int half = 0; half < 2; half++)
                    wk[hh][mt][half] = *(const bf16x8*)(Wkf +
                        (size_t)(((sp * 2 + mt) * 16 + h0 + hh) * 2 + half) * 512 + lane * 8);
        __builtin_amdgcn_sched_barrier(0);

        // ---- 2. DMA slice sp+1 (youngest)
#pragma unroll
        for (int m = 0; m < 2; m++) {
            const int row = 2 * wave + m;
            gld_lds16((const bf16*)(mk + (size_t)(bt * 16 + row) * 8192 + gk * 1024 + ni + gg4 * 4),
                      (bf16*)&Ml[nb][row * 256]);
        }
        __builtin_amdgcn_sched_barrier(0);

        // ---- 3. wait wk + own DMA(sp) (leaves DMA(sp+1) in flight); U-gen
        asm volatile("s_waitcnt vmcnt(2)" ::: "memory");
        __builtin_amdgcn_sched_barrier(0);
#pragma unroll
        for (int hh = 0; hh < 2; hh++) {
            const int h = h0 + hh;
#pragma unroll
            for (int mt = 0; mt < 2; mt++) {
                f32x4 c4;
                c4[0] = 0.f; c4[1] = 0.f; c4[2] = 0.f; c4[3] = 0.f;
                c4 = __builtin_amdgcn_mfma_f32_16x16x32_bf16(wk[hh][mt][0], qf[hh][0], c4, 0, 0, 0);
                c4 = __builtin_amdgcn_mfma_f32_16x16x32_bf16(wk[hh][mt][1], qf[hh][1], c4, 0, 0, 0);
                bf16x4 o;
                o[0] = (bf16)c4[0]; o[1] = (bf16)c4[1]; o[2] = (bf16)c4[2]; o[3] = (bf16)c4[3];
                // Ul[b=lm][h][i_local = mt*16 + q*4 + r]
                *(bf16x4*)((char*)Ul + ((((lm * 16 + h) * 32 + mt * 16 + q * 4) * 2)
                                        ^ (((lm ^ h) & 7) << 4))) = o;
            }
        }
        block_barrier();   // Ul visible (lgkm only; DMA stays in flight)

        // ---- 4. score accumulate: wave's 2 rows, one MFMA each
#pragma unroll
        for (int lb = 0; lb < 2; lb++) {
            const int bb = wave * 2 + lb;
            // A-frag: rows = h (lm), k-slots = i (q*8+j)
            const bf16x8 ua = *(const bf16x8*)((char*)Ul +
                ((((bb * 16 + lm) * 32 + q * 8) * 2) ^ (((bb ^ lm) & 7) << 4)));
            // B-frag: col = k (lm&7 dup), k-slots = i; from Ml[cb]
            const int mbase = bb * 256 + (lane & 7) * 4;   // wait: need kk from lm
            (void)mbase;
            const int kk = lm & 7;
            const f32x4 a0 = *(const f32x4*)&Ml[cb][bb * 256 + (q * 2) * 32 + kk * 4];
            const f32x4 a1 = *(const f32x4*)&Ml[cb][bb * 256 + (q * 2 + 1) * 32 + kk * 4];
            bf16x8 mb;
            mb[0] = (bf16)a0[0]; mb[1] = (bf16)a0[1]; mb[2] = (bf16)a0[2]; mb[3] = (bf16)a0[3];
            mb[4] = (bf16)a1[0]; mb[5] = (bf16)a1[1]; mb[6] = (bf16)a1[2]; mb[7] = (bf16)a1[3];
            sacc[lb] = __builtin_amdgcn_mfma_f32_16x16x32_bf16(ua, mb, sacc[lb], 0, 0, 0);
        }
        block_barrier();   // Ul + Ml[cb] consumed; safe to overwrite
    }

    // ---- softmax over k (cols duplicated across lm and lm+8) + store attn
#pragma unroll
    for (int lb = 0; lb < 2; lb++) {
        const size_t bb = (size_t)(bt * 16 + wave * 2 + lb);
#pragma unroll
        for (int r = 0; r < 4; r++) {
            float s = sacc[lb][r] * 0.125f;          // DH^-0.5
            float mx = s;
            mx = fmaxf(mx, __shfl_xor(mx, 1));
            mx = fmaxf(mx, __shfl_xor(mx, 2));
            mx = fmaxf(mx, __shfl_xor(mx, 4));
            mx = fmaxf(mx, __shfl_xor(mx, 8));
            const float e = __expf(s - mx);
            float d = e;
            d += __shfl_xor(d, 1);
            d += __shfl_xor(d, 2);
            d += __shfl_xor(d, 4);
            d += __shfl_xor(d, 8);                   // = 2 * true denom
            const float a = e * (2.f / d);
            if (lm < 8) attn[bb * 128 + (q * 4 + r) * 8 + lm] = a;
        }
    }
}

// ---------------------------------------------------------------------------
// Fused apply kernel v10 (verified R11): fragment-major Wvf + DMA mv staging.
// ---------------------------------------------------------------------------
__global__ __launch_bounds__(512, 4)
void apply_attn(const float* __restrict__ attn, const float* __restrict__ mv,
                const bf16* __restrict__ Wvf, bf16* __restrict__ OH)
{
    __shared__ float Vl32[3][4096];    // 3x16KB [16 rows][8 k][32 i] fp32, LINEAR
    __shared__ bf16  Wl[16 * 16 * 32]; // 16KB [b][h][32 i] swz ^(((b^h)&7)<<4)

    const int tid  = threadIdx.x;
    const int wave = tid >> 6, lane = tid & 63;
    const int lm = lane & 15, q = lane >> 4;
    const int b0 = blockIdx.x * 16;
    const int h0 = wave * 2;

    const int gk = lane >> 3, gi4 = (lane & 7) * 4;

    bf16x8 afv[2][2];
#pragma unroll
    for (int lb = 0; lb < 2; lb++) {
        const float* ap = attn + (size_t)(b0 + wave * 2 + lb) * 128 + lm * 8;
        const float4 x = *(const float4*)(ap);
        const float4 y = *(const float4*)(ap + 4);
        bf16 a8[8];
        a8[0] = (bf16)x.x; a8[1] = (bf16)x.y; a8[2] = (bf16)x.z; a8[3] = (bf16)x.w;
        a8[4] = (bf16)y.x; a8[5] = (bf16)y.y; a8[6] = (bf16)y.z; a8[7] = (bf16)y.w;
#pragma unroll
        for (int mt = 0; mt < 2; mt++) {
            bf16x8 t;
#pragma unroll
            for (int j = 0; j < 8; j++) t[j] = (q == mt) ? a8[j] : (bf16)0.f;
            afv[lb][mt] = t;
        }
    }

    f32x4 oacc[2][4];
#pragma unroll
    for (int i = 0; i < 2; i++)
#pragma unroll
        for (int j = 0; j < 4; j++)
#pragma unroll
            for (int r = 0; r < 4; r++) oacc[i][j][r] = 0.f;

#pragma unroll
    for (int m = 0; m < 2; m++) {
        const int row = 2 * wave + m;
        gld_lds16((const bf16*)(mv + (size_t)(b0 + row) * 8192 + gk * 1024 + gi4),
                  (bf16*)&Vl32[0][row * 256]);
    }
#pragma unroll
    for (int m = 0; m < 2; m++) {
        const int row = 2 * wave + m;
        gld_lds16((const bf16*)(mv + (size_t)(b0 + row) * 8192 + gk * 1024 + 32 + gi4),
                  (bf16*)&Vl32[1][row * 256]);
    }

    for (int sp = 0; sp < 32; ++sp) {
        const int ni = (sp + 2 < 32) ? sp * 32 + 64 : 0;
        const int cb = sp % 3, nb = (sp + 2) % 3;

        bf16x8 wb[2][4];
#pragma unroll
        for (int hh = 0; hh < 2; hh++) {
            const int h = h0 + hh;
#pragma unroll
            for (int dt = 0; dt < 4; dt++)
                wb[hh][dt] = *(const bf16x8*)(Wvf +
                    ((((size_t)h * 32 + sp) * 4 + dt) * 512 + lane * 8));
        }
        __builtin_amdgcn_sched_barrier(0);

#pragma unroll
        for (int m = 0; m < 2; m++) {
            const int row = 2 * wave + m;
            gld_lds16((const bf16*)(mv + (size_t)(b0 + row) * 8192 + gk * 1024 + ni + gi4),
                      (bf16*)&Vl32[nb][row * 256]);
        }
        __builtin_amdgcn_sched_barrier(0);

        asm volatile("s_waitcnt vmcnt(12)" ::: "memory");
        __builtin_amdgcn_sched_barrier(0);
#pragma unroll
        for (int lb = 0; lb < 2; lb++) {
            const int row = 2 * wave + lb;
            const int il = (q & 1) * 16 + lm;
            float v[8];
#pragma unroll
            for (int k = 0; k < 8; k++) v[k] = Vl32[cb][row * 256 + k * 32 + il];
            bf16x8 avf;
#pragma unroll
            for (int k = 0; k < 8; k++) avf[k] = (bf16)v[k];
#pragma unroll
            for (int mt = 0; mt < 2; mt++) {
                f32x4 c;
                c[0] = 0.f; c[1] = 0.f; c[2] = 0.f; c[3] = 0.f;
                c = __builtin_amdgcn_mfma_f32_16x16x32_bf16(avf, afv[lb][mt], c, 0, 0, 0);
                bf16x4 o;
                o[0] = (bf16)c[0]; o[1] = (bf16)c[1]; o[2] = (bf16)c[2]; o[3] = (bf16)c[3];
                *(bf16x4*)((char*)Wl + ((((row * 16 + lm) * 32 + mt * 16 + q * 4) * 2)
                                        ^ (((row ^ lm) & 7) << 4))) = o;
            }
        }
        block_barrier();

        asm volatile("s_waitcnt vmcnt(2)" ::: "memory");
        __builtin_amdgcn_sched_barrier(0);
#pragma unroll
        for (int hh = 0; hh < 2; hh++) {
            const int h = h0 + hh;
            const bf16x8 wa = *(const bf16x8*)((char*)Wl +
                ((((lm * 16 + h) * 32 + q * 8) * 2) ^ (((lm ^ h) & 7) << 4)));
#pragma unroll
            for (int dt = 0; dt < 4; dt++)
                oacc[hh][dt] = __builtin_amdgcn_mfma_f32_16x16x32_bf16(wa, wb[hh][dt], oacc[hh][dt], 0, 0, 0);
        }
        block_barrier();
    }

#pragma unroll
    for (int hh = 0; hh < 2; hh++) {
        const int h = h0 + hh;
#pragma unroll
        for (int dt = 0; dt < 4; dt++) {
#pragma unroll
            for (int r = 0; r < 4; r++)
                OH[(size_t)(b0 + q * 4 + r) * 1024 + h * 64 + dt * 16 + lm] = (bf16)oacc[hh][dt][r];
        }
    }
}

// ---------------------------------------------------------------------------
// sigmoid gate + residual + LayerNorm. One block per row.
// ---------------------------------------------------------------------------
__global__ __launch_bounds__(256)
void gate_ln_kernel(const float* __restrict__ hs, const float* __restrict__ mo,
                    const float* __restrict__ z,  const float* __restrict__ bg,
                    const float* __restrict__ lng, const float* __restrict__ lnb,
                    float* __restrict__ out)
{
    __shared__ float s1[4], s2[4];
    const int tid = threadIdx.x;
    const size_t base = (size_t)blockIdx.x * 1024 + tid * 4;

    const float4 h4 = *(const float4*)&hs[base];
    const float4 m4 = *(const float4*)&mo[base];
    const float4 z4 = *(const float4*)&z[base];
    const float4 bg4 = *(const float4*)&bg[tid * 4];

    float a[4];
    {
        const float g0 = 1.f / (1.f + __expf(-(z4.x + bg4.x)));
        const float g1 = 1.f / (1.f + __expf(-(z4.y + bg4.y)));
        const float g2 = 1.f / (1.f + __expf(-(z4.z + bg4.z)));
        const float g3 = 1.f / (1.f + __expf(-(z4.w + bg4.w)));
        a[0] = h4.x + g0 * m4.x;
        a[1] = h4.y + g1 * m4.y;
        a[2] = h4.z + g2 * m4.z;
        a[3] = h4.w + g3 * m4.w;
    }
    float sum = a[0] + a[1] + a[2] + a[3];
    float sq  = a[0]*a[0] + a[1]*a[1] + a[2]*a[2] + a[3]*a[3];
#pragma unroll
    for (int off = 32; off >= 1; off >>= 1) {
        sum += __shfl_xor(sum, off);
        sq  += __shfl_xor(sq,  off);
    }
    const int wave = tid >> 6;
    if ((tid & 63) == 0) { s1[wave] = sum; s2[wave] = sq; }
    __syncthreads();
    const float mean = (s1[0] + s1[1] + s1[2] + s1[3]) * (1.f / 1024.f);
    const float var  = (s2[0] + s2[1] + s2[2] + s2[3]) * (1.f / 1024.f) - mean * mean;
    const float inv  = rsqrtf(var + 1e-5f);

    const float4 g4 = *(const float4*)&lng[tid * 4];
    const float4 b4 = *(const float4*)&lnb[tid * 4];
    float4 o;
    o.x = (a[0] - mean) * inv * g4.x + b4.x;
    o.y = (a[1] - mean) * inv * g4.y + b4.y;
    o.z = (a[2] - mean) * inv * g4.z + b4.z;
    o.w = (a[3] - mean) * inv * g4.w + b4.w;
    *(float4*)&out[base] = o;
}

// ---------------------------------------------------------------------------
extern "C" void kernel_launch(void* const* d_in, const int* in_sizes, int n_in,
                              void* d_out, int out_size, void* d_ws, size_t ws_size,
                              hipStream_t stream)
{
    const float* hs  = (const float*)d_in[0];
    const float* mk  = (const float*)d_in[1];
    const float* mv  = (const float*)d_in[2];
    const float* Wq  = (const float*)d_in[3];
    const float* Wk  = (const float*)d_in[4];
    const float* Wv  = (const float*)d_in[5];
    const float* Wo  = (const float*)d_in[6];
    const float* Wg  = (const float*)d_in[7];
    const float* bg  = (const float*)d_in[8];
    const float* lng = (const float*)d_in[9];
    const float* lnb = (const float*)d_in[10];
    float* out = (float*)d_out;

    const int B = 8192;
    const dim3 tb(256);

    char* ws = (char*)d_ws;
    bf16*  Wq_t = (bf16*)(ws);                        // 2 MB  (1024x1024, N x K)
    bf16*  Wv_t = (bf16*)(ws + ((size_t)2  << 20));   // 2 MB
    bf16*  Wo_t = (bf16*)(ws + ((size_t)4  << 20));   // 2 MB
    bf16*  Wg_t = (bf16*)(ws + ((size_t)6  << 20));   // 4 MB  (1024x2048)
    bf16*  Wk_b = (bf16*)(ws + ((size_t)10 << 20));   // 2 MB  (1024x1024, NOT transposed)
    bf16*  hs_b = (bf16*)(ws + ((size_t)12 << 20));   // 16 MB (8192x1024)
    bf16*  Qb   = (bf16*)(ws + ((size_t)28 << 20));   // 16 MB
    bf16*  OH   = (bf16*)(ws + ((size_t)44 << 20));   // 16 MB
    float* Mo   = (float*)(ws + ((size_t)60 << 20));  // 32 MB
    bf16*  Mo_b = (bf16*)(ws + ((size_t)92 << 20));   // 16 MB
    float* Zb   = (float*)(ws + ((size_t)108 << 20)); // 32 MB
    float* At   = (float*)(ws + ((size_t)140 << 20)); // 4 MB  (8192x16x8 fp32)
    bf16*  Wvf  = (bf16*)(ws + ((size_t)208 << 20));  // 2 MB  (fragment-major Wv)
    bf16*  Wkf  = (bf16*)(ws + ((size_t)210 << 20));  // 2 MB  (fragment-major Wk, 32-i)
    bf16*  Qf   = (bf16*)(ws + ((size_t)212 << 20));  // 16 MB (fragment-major Q)

    transpose_cvt<<<dim3(32, 32), tb, 0, stream>>>(Wq, Wq_t, 1024, 1024);
    transpose_cvt<<<dim3(32, 32), tb, 0, stream>>>(Wv, Wv_t, 1024, 1024);
    transpose_cvt<<<dim3(32, 32), tb, 0, stream>>>(Wo, Wo_t, 1024, 1024);
    transpose_cvt<<<dim3(32, 64), tb, 0, stream>>>(Wg, Wg_t, 2048, 1024);
    cvt_bf16<<<dim3(1024 * 1024 / 8 / 256), tb, 0, stream>>>(Wk, Wk_b, 1024 * 1024 / 8);
    cvt_bf16<<<dim3(B * 1024 / 8 / 256), tb, 0, stream>>>(hs, hs_b, B * 1024 / 8);
    repack_wv<<<dim3(512), tb, 0, stream>>>(Wv_t, Wvf);
    repack_wk2<<<dim3(512), tb, 0, stream>>>(Wk_b, Wkf);

    // Q = hs @ Wq -> bf16 (B x 1024)
    gemm_a97<false><<<dim3(8, 64, 1), tb, 0, stream>>>(
        hs_b, nullptr, Wq_t, nullptr, Qb,
        1024, 1024, 1024, 0, 1024, 1024, 0, 0, 0);
    // fragment-major Q for the score kernel
    repack_q<<<dim3(4096), tb, 0, stream>>>(Qb, Qf);
    // fused: U-gen + scores + softmax -> attn (B x 16 x 8 fp32)
    score_attn<<<dim3(B / 16), dim3(512), 0, stream>>>(Qf, Wkf, mk, At);
    // fused: W_mix-gen + V-proj -> OH (B x 1024 bf16)
    apply_attn<<<dim3(B / 16), dim3(512), 0, stream>>>(At, mv, Wvf, OH);
    // memory_out = OH @ Wo -> fp32 Mo + bf16 Mo_b
    gemm_a97<false><<<dim3(8, 64, 1), tb, 0, stream>>>(
        OH, nullptr, Wo_t, Mo, Mo_b,
        1024, 1024, 1024, 0, 1024, 1024, 0, 0, 0);
    // z = [hs, Mo] @ Wg -> fp32
    gemm_a97<true><<<dim3(8, 64, 1), tb, 0, stream>>>(
        hs_b, Mo_b, Wg_t, Zb, nullptr,
        2048, 1024, 1024, 1024, 2048, 1024, 0, 0, 0);
    // gate + residual + LayerNorm
    gate_ln_kernel<<<dim3(B), tb, 0, stream>>>(
        hs, Mo, Zb, bg, lng, lnb, out);
}